// Round 5
// baseline (110.866 us; speedup 1.0000x reference)
//
#include <hip/hip_runtime.h>

// Problem constants (from reference): B=16384, D=255, K=4, L=16, T=1020
constexpr int T_TUN = 1020;
constexpr int D_DST = 255;
constexpr int L_LNK = 16;
constexpr float EPS = 1e-8f;
constexpr int ROWS_PER_BLOCK = 8;   // 4 waves x 2 rows (float2-packed)

__device__ __forceinline__ float read_lane_f(float v, int l) {
  return __builtin_bit_cast(float,
      __builtin_amdgcn_readlane(__builtin_bit_cast(int, v), l));
}

__global__ __launch_bounds__(256) void rowloss_kernel(
    const float* __restrict__ pred,     // [B, T]
    const float* __restrict__ demands,  // [B, D]
    const float* __restrict__ cur,      // [B, L]
    const float* __restrict__ caps,     // [L]
    const int*   __restrict__ t2l,      // [T]
    float* __restrict__ partials)       // [gridDim.x * 4]
{
  const int tid  = threadIdx.x;
  const int lane = tid & 63;
  const int w    = tid >> 6;   // wave id 0..3

  // float2-packed bins: pb[link*64 + lane] = (rowA_acc, rowB_acc).
  //  - one b64 RMW per scatter step carries BOTH rows (16 RMW/pair vs 32)
  //  - b64 bank spread: 128 dwords over 32 banks = 4/bank = ideal
  //  - plain RMW, NOT ds atomics (R1: atomics 4x slower)
  //  - LDS EXACTLY 32 KB/block (no wacc) -> 5 blocks/CU = 20 waves/CU
  //    (R2-R4 showed TLP is the dominant latency hider: 16+ waves/CU >> 8)
  __shared__ float2 bins_all[4][L_LNK * 64];   // 8 KB/wave, 32 KB/block
  float2* pb = bins_all[w];

  const int b16 = lane & 15;       // this lane's bin for the reduce/stats
  const int g   = lane >> 4;       // lane group 0..3
  const float capinv = 1.0f / (caps[b16] + EPS);

  // Row-invariant scatter offsets: float2 index = link*64 + lane
  int off[4][4];
  bool dv[4];
#pragma unroll
  for (int j = 0; j < 4; ++j) {
    const int d = lane + 64 * j;
    dv[j] = (d < D_DST);
    const int dd = dv[j] ? d : 0;
    const int4 lk = ((const int4*)t2l)[dd];   // t2l[4d..4d+3]
    off[j][0] = lk.x * 64 + lane;
    off[j][1] = lk.y * 64 + lane;
    off[j][2] = lk.z * 64 + lane;
    off[j][3] = lk.w * 64 + lane;
  }

  const int row0 = blockIdx.x * ROWS_PER_BLOCK + w * 2;

  // ---- issue ALL global loads for both rows up front (max MLP) ----
  float4 r4[2][4];
  float  dm[2][4];
  float  mycur[2];
#pragma unroll
  for (int r = 0; r < 2; ++r) {
    const int b = row0 + r;
    const float4* prow = (const float4*)(pred + (size_t)b * T_TUN);
    const float*  drow = demands + (size_t)b * D_DST;
    mycur[r] = cur[(size_t)b * L_LNK + b16];
#pragma unroll
    for (int j = 0; j < 4; ++j) {
      const int d = lane + 64 * j;
      if (dv[j]) { r4[r][j] = prow[d]; dm[r][j] = drow[d]; }
      else       { r4[r][j] = make_float4(0.f,0.f,0.f,0.f); dm[r][j] = 0.f; }
    }
  }

  // zero the 8KB float2 region: 8x ds_write_b128
  {
    const float4 z = make_float4(0.f, 0.f, 0.f, 0.f);
    float4* pz = (float4*)pb;
#pragma unroll
    for (int i = 0; i < 8; ++i) pz[lane + 64 * i] = z;
  }

  __builtin_amdgcn_wave_barrier();  // zeroes before scatter (DS pipe in-order)

  // scatter: 16 b64 RMW steps, each carrying BOTH rows of the pair.
  // Branch-free: invalid lane (63,j=3) contributes v*0 into d=0's slots.
#pragma unroll
  for (int j = 0; j < 4; ++j) {
    const float4 vA = r4[0][j]; const float dA = dm[0][j];
    const float4 vB = r4[1][j]; const float dB = dm[1][j];
    { const int o = off[j][0]; float2 s = pb[o];
      s.x = fmaf(vA.x, dA, s.x); s.y = fmaf(vB.x, dB, s.y); pb[o] = s; }
    { const int o = off[j][1]; float2 s = pb[o];
      s.x = fmaf(vA.y, dA, s.x); s.y = fmaf(vB.y, dB, s.y); pb[o] = s; }
    { const int o = off[j][2]; float2 s = pb[o];
      s.x = fmaf(vA.z, dA, s.x); s.y = fmaf(vB.z, dB, s.y); pb[o] = s; }
    { const int o = off[j][3]; float2 s = pb[o];
      s.x = fmaf(vA.w, dA, s.x); s.y = fmaf(vB.w, dB, s.y); pb[o] = s; }
  }

  __builtin_amdgcn_wave_barrier();  // scatter before reduce reads

  // column reduce, bank-conflict-free via b16-rotated slot order (R4-verified):
  // float4 slot s holds copies (2s,2s+1) of bin b16 as (A,B,A,B);
  // rotation spreads the 16 b16-groups over all 32 banks.
  float csA = 0.0f, csB = 0.0f;
  {
    const float4* pr = (const float4*)(pb + b16 * 64 + 16 * g);
#pragma unroll
    for (int jj = 0; jj < 8; ++jj) {
      const float4 v = pr[(jj + b16) & 7];
      csA += v.x + v.z;
      csB += v.y + v.w;
    }
  }
  csA += __shfl_xor(csA, 16, 64);
  csA += __shfl_xor(csA, 32, 64);
  csB += __shfl_xor(csB, 16, 64);
  csB += __shfl_xor(csB, 32, 64);

  const float uA = csA * capinv;
  const float uB = csB * capinv;

  // fused stats: group 0 sums u, 1 sums u^2, 2 sums u*cur, 3 maxes u
  float valA = (g == 0) ? uA : (g == 1) ? (uA * uA)
             : (g == 2) ? (uA * mycur[0]) : uA;
  float valB = (g == 0) ? uB : (g == 1) ? (uB * uB)
             : (g == 2) ? (uB * mycur[1]) : uB;
#pragma unroll
  for (int m = 1; m < 16; m <<= 1) {
    const float oA  = __shfl_xor(valA, m, 64);
    const float smA = valA + oA;
    const float mmA = fmaxf(valA, oA);
    valA = (g == 3) ? mmA : smA;
    const float oB  = __shfl_xor(valB, m, 64);
    const float smB = valB + oB;
    const float mmB = fmaxf(valB, oB);
    valB = (g == 3) ? mmB : smB;
  }
  float acc = 0.0f;
  {
    const float s1 = read_lane_f(valA, 0);
    const float s2 = read_lane_f(valA, 16);
    const float s3 = read_lane_f(valA, 32);
    const float mx = read_lane_f(valA, 48);
    const float var = (s2 - s1 * s1 * (1.0f / 16.0f)) * (1.0f / 15.0f); // ddof=1
    acc += 0.3f * var + 0.5f * s3 + 0.2f * mx;
  }
  {
    const float s1 = read_lane_f(valB, 0);
    const float s2 = read_lane_f(valB, 16);
    const float s3 = read_lane_f(valB, 32);
    const float mx = read_lane_f(valB, 48);
    const float var = (s2 - s1 * s1 * (1.0f / 16.0f)) * (1.0f / 15.0f);
    acc += 0.3f * var + 0.5f * s3 + 0.2f * mx;
  }

  // per-wave partial straight to global: no wacc LDS, no __syncthreads
  if (lane == 0) partials[blockIdx.x * 4 + w] = acc;
}

__global__ __launch_bounds__(256) void reduce_kernel(
    const float* __restrict__ partials, int n, float* __restrict__ out, float invB)
{
  __shared__ float s[256];
  const int tid = threadIdx.x;
  const float4* p4 = (const float4*)partials;
  const int n4 = n >> 2;
  float a = 0.0f;
  for (int i = tid; i < n4; i += 256) {
    const float4 v = p4[i];
    a += v.x + v.y + v.z + v.w;
  }
  s[tid] = a;
  __syncthreads();
  for (int st = 128; st > 0; st >>= 1) {
    if (tid < st) s[tid] += s[tid + st];
    __syncthreads();
  }
  if (tid == 0) out[0] = s[0] * invB;
}

extern "C" void kernel_launch(void* const* d_in, const int* in_sizes, int n_in,
                              void* d_out, int out_size, void* d_ws, size_t ws_size,
                              hipStream_t stream) {
  const float* pred    = (const float*)d_in[0];  // [B, T]
  const float* demands = (const float*)d_in[1];  // [B, D]
  const float* cur     = (const float*)d_in[2];  // [B, L]
  const float* caps    = (const float*)d_in[3];  // [L]
  const int*   t2l     = (const int*)d_in[4];    // [T]
  float* out = (float*)d_out;

  const int L = in_sizes[3];          // 16
  const int B = in_sizes[2] / L;      // 16384

  const int grid = B / ROWS_PER_BLOCK;  // 2048
  float* partials = (float*)d_ws;       // grid*4 floats (per-wave partials)

  rowloss_kernel<<<grid, 256, 0, stream>>>(pred, demands, cur, caps, t2l, partials);
  reduce_kernel<<<1, 256, 0, stream>>>(partials, grid * 4, out, 1.0f / (float)B);
}

// Round 6
// 109.161 us; speedup vs baseline: 1.0156x; 1.0156x over previous
//
#include <hip/hip_runtime.h>

// Problem constants (from reference): B=16384, D=255, K=4, L=16, T=1020
constexpr int T_TUN = 1020;
constexpr int D_DST = 255;
constexpr int L_LNK = 16;
constexpr float EPS = 1e-8f;
constexpr int ROWS_PER_BLOCK = 8;   // 4 waves x 2 rows (two b32 regions per wave)

__device__ __forceinline__ float read_lane_f(float v, int l) {
  return __builtin_bit_cast(float,
      __builtin_amdgcn_readlane(__builtin_bit_cast(int, v), l));
}

__global__ __launch_bounds__(256) void rowloss_kernel(
    const float* __restrict__ pred,     // [B, T]
    const float* __restrict__ demands,  // [B, D]
    const float* __restrict__ cur,      // [B, L]
    const float* __restrict__ caps,     // [L]
    const int*   __restrict__ t2l,      // [T]
    float* __restrict__ partials)       // [gridDim.x * 4]
{
  const int tid  = threadIdx.x;
  const int lane = tid & 63;
  const int w    = tid >> 6;   // wave id 0..3

  // Two per-row b32 regions per wave (R2 structure, best measured):
  //  - scatter: 2 INDEPENDENT depth-16 RMW chains (separate __shared__ arrays
  //    -> compiler-provable no-alias -> interleaved, latency overlapped)
  //  - b32 RMW bank = lane&31 -> 2-way aliasing, free (NOT ds atomics: R1 4x slower;
  //    NOT b64-packed: R5 showed it halves chain parallelism, bank-cycle neutral)
  //  - LDS EXACTLY 32 KB/block (no wacc/syncthreads) -> 5 blocks/CU = 20 waves/CU,
  //    40 chains/CU (R2: 33KB -> 4 blocks, 16 waves, 32 chains -> 19.7us)
  __shared__ float pA_all[4][L_LNK * 64];   // 4 KB/wave
  __shared__ float pB_all[4][L_LNK * 64];   // 4 KB/wave
  float* pa = pA_all[w];
  float* pb = pB_all[w];

  const int b16 = lane & 15;       // this lane's bin for the reduce/stats
  const int g   = lane >> 4;       // lane group 0..3
  const float capinv = 1.0f / (caps[b16] + EPS);

  // Row-invariant scatter offsets: element index = link*64 + lane
  int off[4][4];
  bool dv[4];
#pragma unroll
  for (int j = 0; j < 4; ++j) {
    const int d = lane + 64 * j;
    dv[j] = (d < D_DST);
    const int dd = dv[j] ? d : 0;
    const int4 lk = ((const int4*)t2l)[dd];   // t2l[4d..4d+3]
    off[j][0] = lk.x * 64 + lane;
    off[j][1] = lk.y * 64 + lane;
    off[j][2] = lk.z * 64 + lane;
    off[j][3] = lk.w * 64 + lane;
  }

  const int row0 = blockIdx.x * ROWS_PER_BLOCK + w * 2;

  // ---- issue ALL global loads for both rows up front (max MLP) ----
  float4 r4[2][4];
  float  dm[2][4];
  float  mycur[2];
#pragma unroll
  for (int r = 0; r < 2; ++r) {
    const int b = row0 + r;
    const float4* prow = (const float4*)(pred + (size_t)b * T_TUN);
    const float*  drow = demands + (size_t)b * D_DST;
    mycur[r] = cur[(size_t)b * L_LNK + b16];
#pragma unroll
    for (int j = 0; j < 4; ++j) {
      const int d = lane + 64 * j;
      if (dv[j]) { r4[r][j] = prow[d]; dm[r][j] = drow[d]; }
      else       { r4[r][j] = make_float4(0.f,0.f,0.f,0.f); dm[r][j] = 0.f; }
    }
  }

  // zero both regions: 8x ds_write_b128
  {
    const float4 z = make_float4(0.f, 0.f, 0.f, 0.f);
    float4* pza = (float4*)pa;
    float4* pzb = (float4*)pb;
#pragma unroll
    for (int i = 0; i < 4; ++i) { pza[lane + 64 * i] = z; pzb[lane + 64 * i] = z; }
  }

  __builtin_amdgcn_wave_barrier();  // zeroes before scatter (DS pipe in-order)

  // scatter: two independent depth-16 may-alias RMW chains, interleaved.
  // Branch-free: invalid lane (63,j=3) contributes v*0 into d=0's slots.
#pragma unroll
  for (int j = 0; j < 4; ++j) {
    const float4 vA = r4[0][j]; const float dA = dm[0][j];
    const float4 vB = r4[1][j]; const float dB = dm[1][j];
    pa[off[j][0]] = fmaf(vA.x, dA, pa[off[j][0]]);
    pb[off[j][0]] = fmaf(vB.x, dB, pb[off[j][0]]);
    pa[off[j][1]] = fmaf(vA.y, dA, pa[off[j][1]]);
    pb[off[j][1]] = fmaf(vB.y, dB, pb[off[j][1]]);
    pa[off[j][2]] = fmaf(vA.z, dA, pa[off[j][2]]);
    pb[off[j][2]] = fmaf(vB.z, dB, pb[off[j][2]]);
    pa[off[j][3]] = fmaf(vA.w, dA, pa[off[j][3]]);
    pb[off[j][3]] = fmaf(vB.w, dB, pb[off[j][3]]);
  }

  __builtin_amdgcn_wave_barrier();  // scatter before reduce reads

  // column reduce, bank-conflict-free via b16-rotated slot order:
  // slot s=(jj+b16)&3 -> dword-bank (16g+4s)%32: every 4-bank group serves
  // exactly 8 of the wave's 256 dwords = optimal 8-cycle b128 reads
  // (un-rotated: s=jj fixed -> 32 lanes on one 4-bank group = 32 cycles).
  float csA = 0.0f, csB = 0.0f;
  {
    const float4* prA = (const float4*)(pa + b16 * 64 + 16 * g);
    const float4* prB = (const float4*)(pb + b16 * 64 + 16 * g);
#pragma unroll
    for (int jj = 0; jj < 4; ++jj) {
      const int s = (jj + b16) & 3;
      const float4 a = prA[s];
      csA += a.x + a.y + a.z + a.w;
      const float4 b = prB[s];
      csB += b.x + b.y + b.z + b.w;
    }
  }
  csA += __shfl_xor(csA, 16, 64);
  csA += __shfl_xor(csA, 32, 64);
  csB += __shfl_xor(csB, 16, 64);
  csB += __shfl_xor(csB, 32, 64);

  const float uA = csA * capinv;
  const float uB = csB * capinv;

  // fused stats: group 0 sums u, 1 sums u^2, 2 sums u*cur, 3 maxes u
  float valA = (g == 0) ? uA : (g == 1) ? (uA * uA)
             : (g == 2) ? (uA * mycur[0]) : uA;
  float valB = (g == 0) ? uB : (g == 1) ? (uB * uB)
             : (g == 2) ? (uB * mycur[1]) : uB;
#pragma unroll
  for (int m = 1; m < 16; m <<= 1) {
    const float oA  = __shfl_xor(valA, m, 64);
    const float smA = valA + oA;
    const float mmA = fmaxf(valA, oA);
    valA = (g == 3) ? mmA : smA;
    const float oB  = __shfl_xor(valB, m, 64);
    const float smB = valB + oB;
    const float mmB = fmaxf(valB, oB);
    valB = (g == 3) ? mmB : smB;
  }
  float acc = 0.0f;
  {
    const float s1 = read_lane_f(valA, 0);
    const float s2 = read_lane_f(valA, 16);
    const float s3 = read_lane_f(valA, 32);
    const float mx = read_lane_f(valA, 48);
    const float var = (s2 - s1 * s1 * (1.0f / 16.0f)) * (1.0f / 15.0f); // ddof=1
    acc += 0.3f * var + 0.5f * s3 + 0.2f * mx;
  }
  {
    const float s1 = read_lane_f(valB, 0);
    const float s2 = read_lane_f(valB, 16);
    const float s3 = read_lane_f(valB, 32);
    const float mx = read_lane_f(valB, 48);
    const float var = (s2 - s1 * s1 * (1.0f / 16.0f)) * (1.0f / 15.0f);
    acc += 0.3f * var + 0.5f * s3 + 0.2f * mx;
  }

  // per-wave partial straight to global: no wacc LDS, no __syncthreads
  if (lane == 0) partials[blockIdx.x * 4 + w] = acc;
}

__global__ __launch_bounds__(256) void reduce_kernel(
    const float* __restrict__ partials, int n, float* __restrict__ out, float invB)
{
  __shared__ float s[256];
  const int tid = threadIdx.x;
  const float4* p4 = (const float4*)partials;
  const int n4 = n >> 2;
  float a = 0.0f;
  for (int i = tid; i < n4; i += 256) {
    const float4 v = p4[i];
    a += v.x + v.y + v.z + v.w;
  }
  s[tid] = a;
  __syncthreads();
  for (int st = 128; st > 0; st >>= 1) {
    if (tid < st) s[tid] += s[tid + st];
    __syncthreads();
  }
  if (tid == 0) out[0] = s[0] * invB;
}

extern "C" void kernel_launch(void* const* d_in, const int* in_sizes, int n_in,
                              void* d_out, int out_size, void* d_ws, size_t ws_size,
                              hipStream_t stream) {
  const float* pred    = (const float*)d_in[0];  // [B, T]
  const float* demands = (const float*)d_in[1];  // [B, D]
  const float* cur     = (const float*)d_in[2];  // [B, L]
  const float* caps    = (const float*)d_in[3];  // [L]
  const int*   t2l     = (const int*)d_in[4];    // [T]
  float* out = (float*)d_out;

  const int L = in_sizes[3];          // 16
  const int B = in_sizes[2] / L;      // 16384

  const int grid = B / ROWS_PER_BLOCK;  // 2048
  float* partials = (float*)d_ws;       // grid*4 floats (per-wave partials)

  rowloss_kernel<<<grid, 256, 0, stream>>>(pred, demands, cur, caps, t2l, partials);
  reduce_kernel<<<1, 256, 0, stream>>>(partials, grid * 4, out, 1.0f / (float)B);
}